// Round 2
// baseline (1422.744 us; speedup 1.0000x reference)
//
#include <hip/hip_runtime.h>
#include <hip/hip_bf16.h>
#include <math.h>

typedef __bf16 bf16_t;
typedef __bf16 bf16x8 __attribute__((ext_vector_type(8)));
typedef float f32x4 __attribute__((ext_vector_type(4)));

// ---------------------------------------------------------------------------
// Problem constants: B=4, H=64, W=128, C=512, F=1024, WS=4, SS=2, NH=8, hd=64.
// M = 32768 token rows. 512 windows/batch, 2048 windows total.
// ---------------------------------------------------------------------------

// Workspace layout (bytes):
//   xf / x1 (fp32, in-place residual) [0, 64M)
//   xw / O / h2 (bf16)                [64M, 96M)
//   qkv / gelu-out a (bf16)           [96M, 192M)
//   weights bf16                      [192M..)
//   small vectors fp32 + dtype flag
#define XF_OFF   0u
#define XW_OFF   67108864u
#define QKV_OFF  100663296u
#define WQ_OFF   201326592u
#define WP_OFF   202899456u
#define W1_OFF   203423744u
#define W2_OFF   204472320u
#define SV_OFF   205520896u
#define FLAG_OFF 205545472u
// small-vector float offsets inside SV block:
//   g1=0 be1=512 bq=1024 bp=2560 g2=3072 be2=3584 b1=4096 b2=5120 rpb=5632 (end 6024)

// Gather permutation: xw row r  <->  original token row perm(r).
// shift(-2) -> window partition equals the inverse of window-reverse -> shift(+2).
__device__ __forceinline__ int perm_row(int r) {
    int b   = r >> 13;
    int rem = r & 8191;
    int w   = rem >> 4;
    int n   = rem & 15;
    int wy  = w >> 5, wx = w & 31;
    int y   = wy * 4 + (n >> 2);
    int x   = wx * 4 + (n & 3);
    int ys  = (y + 2) & 63;
    int xs  = (x + 2) & 127;
    return (b << 13) + (ys << 7) + xs;
}

// ---------------- dtype probe: 1 = fp32 source, 0 = bf16 source ----------------
__global__ __launch_bounds__(256) void k_probe(const unsigned short* __restrict__ x,
                                               int n, int* __restrict__ flag) {
    __shared__ int cnt;
    if (threadIdx.x == 0) cnt = 0;
    __syncthreads();
    int c = 0;
    for (int i = threadIdx.x; i < n; i += 256) {
        int e = (x[i] >> 7) & 0xFF;   // bf16 exponent field
        if (e >= 0xC0) c++;           // |v| >= 2^65 — impossible for sane bf16 data
    }
    atomicAdd(&cnt, c);
    __syncthreads();
    if (threadIdx.x == 0) *flag = (cnt > 8) ? 1 : 0;
}

// ---------------- input normalization ----------------
__global__ __launch_bounds__(256) void k_cvt_bf16(const void* __restrict__ src,
                                                  bf16_t* __restrict__ dst, int n,
                                                  const int* __restrict__ flag) {
    int i = blockIdx.x * 256 + threadIdx.x;
    if (i >= n) return;
    dst[i] = (*flag) ? (bf16_t)((const float*)src)[i] : ((const bf16_t*)src)[i];
}

__global__ __launch_bounds__(256) void k_cvt_f32(const void* __restrict__ src,
                                                 float* __restrict__ dst, int n,
                                                 const int* __restrict__ flag) {
    int i = blockIdx.x * 256 + threadIdx.x;
    if (i >= n) return;
    dst[i] = (*flag) ? ((const float*)src)[i] : (float)((const bf16_t*)src)[i];
}

__global__ __launch_bounds__(256) void k_cvt_small(
        const void* g1, const void* be1, const void* bq, const void* bp,
        const void* g2, const void* be2, const void* b1, const void* b2,
        const void* rpb, float* __restrict__ dst, const int* __restrict__ flag) {
    int i = blockIdx.x * 256 + threadIdx.x;
    const void* src; int off;
    if      (i < 512)  { src = g1;  off = i; }
    else if (i < 1024) { src = be1; off = i - 512; }
    else if (i < 2560) { src = bq;  off = i - 1024; }
    else if (i < 3072) { src = bp;  off = i - 2560; }
    else if (i < 3584) { src = g2;  off = i - 3072; }
    else if (i < 4096) { src = be2; off = i - 3584; }
    else if (i < 5120) { src = b1;  off = i - 4096; }
    else if (i < 5632) { src = b2;  off = i - 5120; }
    else if (i < 6024) { src = rpb; off = i - 5632; }
    else return;
    dst[i] = (*flag) ? ((const float*)src)[off] : (float)((const bf16_t*)src)[off];
}

// ---------------- Kernel 1: LN1 + shift + window partition ----------------
__global__ __launch_bounds__(256) void k_ln1(const float* __restrict__ x,
                                             const float* __restrict__ g,
                                             const float* __restrict__ be,
                                             bf16_t* __restrict__ xw) {
    int r    = blockIdx.x * 4 + (threadIdx.x >> 6);
    int lane = threadIdx.x & 63;
    const float* xr = x + (long)perm_row(r) * 512;
    int base = lane * 8;
    float v[8];
    float s = 0.f, ss = 0.f;
#pragma unroll
    for (int j = 0; j < 8; j++) {
        float t = xr[base + j];
        v[j] = t; s += t; ss += t * t;
    }
#pragma unroll
    for (int off = 32; off; off >>= 1) {
        s  += __shfl_down(s,  off, 64);
        ss += __shfl_down(ss, off, 64);
    }
    s  = __shfl(s, 0, 64);
    ss = __shfl(ss, 0, 64);
    float m   = s * (1.f / 512.f);
    float var = ss * (1.f / 512.f) - m * m;
    float inv = rsqrtf(var + 1e-5f);
    bf16_t* orow = xw + (long)r * 512;
#pragma unroll
    for (int j = 0; j < 8; j++)
        orow[base + j] = (bf16_t)((v[j] - m) * inv * g[base + j] + be[base + j]);
}

// ---------------- Kernel 5: LN2 ----------------
__global__ __launch_bounds__(256) void k_ln2(const float* __restrict__ x1,
                                             const float* __restrict__ g,
                                             const float* __restrict__ be,
                                             bf16_t* __restrict__ h2) {
    int r    = blockIdx.x * 4 + (threadIdx.x >> 6);
    int lane = threadIdx.x & 63;
    const float* xr = x1 + (long)r * 512;
    int base = lane * 8;
    float v[8];
    float s = 0.f, ss = 0.f;
#pragma unroll
    for (int j = 0; j < 8; j++) {
        float t = xr[base + j];
        v[j] = t; s += t; ss += t * t;
    }
#pragma unroll
    for (int off = 32; off; off >>= 1) {
        s  += __shfl_down(s,  off, 64);
        ss += __shfl_down(ss, off, 64);
    }
    s  = __shfl(s, 0, 64);
    ss = __shfl(ss, 0, 64);
    float m   = s * (1.f / 512.f);
    float var = ss * (1.f / 512.f) - m * m;
    float inv = rsqrtf(var + 1e-5f);
    bf16_t* orow = h2 + (long)r * 512;
#pragma unroll
    for (int j = 0; j < 8; j++)
        orow[base + j] = (bf16_t)((v[j] - m) * inv * g[base + j] + be[base + j]);
}

// ---------------- Shared MFMA GEMM core (verified m92 gemm_bt pattern) -----
// One wave computes a 16x64 C strip. A:[M,K] bf16 row-major, W:[N,K] bf16
// row-major (C = A @ W^T). A/B frag: [idx=lane&15][k=(lane>>4)*8+j].
// C/D: row=(lane>>4)*4+reg (M side), col=lane&15 (N side).
__device__ __forceinline__ void gemm_core(const bf16_t* __restrict__ A,
                                          const bf16_t* __restrict__ W,
                                          int K, int m_base, int n_base,
                                          f32x4 acc[4]) {
    int lane = threadIdx.x & 63;
    int rr   = lane & 15, quad = lane >> 4;
    const bf16_t* Ar = A + (long)(m_base + rr) * K + quad * 8;
    const bf16_t* W0 = W + (long)(n_base + rr) * K + quad * 8;
#pragma unroll
    for (int t = 0; t < 4; t++) { f32x4 z = {0.f, 0.f, 0.f, 0.f}; acc[t] = z; }
    for (int k = 0; k < K; k += 32) {
        bf16x8 a = *(const bf16x8*)(Ar + k);
#pragma unroll
        for (int t = 0; t < 4; t++) {
            bf16x8 b = *(const bf16x8*)(W0 + (long)t * 16 * K + k);
            acc[t] = __builtin_amdgcn_mfma_f32_16x16x32_bf16(a, b, acc[t], 0, 0, 0);
        }
    }
}

// ---------------- Kernel 2: QKV GEMM + bias ----------------
__global__ __launch_bounds__(256) void k_gemm_qkv(const bf16_t* __restrict__ A,
                                                  const bf16_t* __restrict__ W,
                                                  const float* __restrict__ bias,
                                                  bf16_t* __restrict__ C,
                                                  int N, int K) {
    int wave   = threadIdx.x >> 6;
    int m_base = (blockIdx.y * 4 + wave) * 16;
    int n_base = blockIdx.x * 64;
    f32x4 acc[4];
    gemm_core(A, W, K, m_base, n_base, acc);
    int lane = threadIdx.x & 63, quad = lane >> 4, cn = lane & 15;
#pragma unroll
    for (int t = 0; t < 4; t++) {
        int col  = n_base + t * 16 + cn;
        float bb = bias[col];
#pragma unroll
        for (int i = 0; i < 4; i++) {
            int row = m_base + quad * 4 + i;
            C[(long)row * N + col] = (bf16_t)(acc[t][i] + bb);
        }
    }
}

// ---------------- Kernel 4: proj GEMM + bias + residual (in-place xf) ------
__global__ __launch_bounds__(256) void k_gemm_proj(const bf16_t* __restrict__ A,
                                                   const bf16_t* __restrict__ W,
                                                   const float* __restrict__ bias,
                                                   float* __restrict__ x1,
                                                   int N, int K) {
    int wave   = threadIdx.x >> 6;
    int m_base = (blockIdx.y * 4 + wave) * 16;
    int n_base = blockIdx.x * 64;
    f32x4 acc[4];
    gemm_core(A, W, K, m_base, n_base, acc);
    int lane = threadIdx.x & 63, quad = lane >> 4, cn = lane & 15;
#pragma unroll
    for (int t = 0; t < 4; t++) {
        int col  = n_base + t * 16 + cn;
        float bb = bias[col];
#pragma unroll
        for (int i = 0; i < 4; i++) {
            int row = m_base + quad * 4 + i;
            long o  = (long)perm_row(row) * 512 + col;
            x1[o]   = x1[o] + acc[t][i] + bb;   // each element touched exactly once
        }
    }
}

// ---------------- Kernel 6: FC1 GEMM + bias + exact GELU ----------------
__global__ __launch_bounds__(256) void k_gemm_fc1(const bf16_t* __restrict__ A,
                                                  const bf16_t* __restrict__ W,
                                                  const float* __restrict__ bias,
                                                  bf16_t* __restrict__ C,
                                                  int N, int K) {
    int wave   = threadIdx.x >> 6;
    int m_base = (blockIdx.y * 4 + wave) * 16;
    int n_base = blockIdx.x * 64;
    f32x4 acc[4];
    gemm_core(A, W, K, m_base, n_base, acc);
    int lane = threadIdx.x & 63, quad = lane >> 4, cn = lane & 15;
#pragma unroll
    for (int t = 0; t < 4; t++) {
        int col  = n_base + t * 16 + cn;
        float bb = bias[col];
#pragma unroll
        for (int i = 0; i < 4; i++) {
            int row = m_base + quad * 4 + i;
            float v = acc[t][i] + bb;
            float ge = 0.5f * v * (1.f + erff(v * 0.70710678118654752f));
            C[(long)row * N + col] = (bf16_t)ge;
        }
    }
}

// ---------------- Kernel 7: FC2 GEMM + bias + residual -> out ----------------
__global__ __launch_bounds__(256) void k_gemm_fc2(const bf16_t* __restrict__ A,
                                                  const bf16_t* __restrict__ W,
                                                  const float* __restrict__ bias,
                                                  const float* __restrict__ x1,
                                                  void* __restrict__ out,
                                                  const int* __restrict__ flag,
                                                  int N, int K) {
    int wave   = threadIdx.x >> 6;
    int m_base = (blockIdx.y * 4 + wave) * 16;
    int n_base = blockIdx.x * 64;
    f32x4 acc[4];
    gemm_core(A, W, K, m_base, n_base, acc);
    int lane = threadIdx.x & 63, quad = lane >> 4, cn = lane & 15;
    int f = *flag;
#pragma unroll
    for (int t = 0; t < 4; t++) {
        int col  = n_base + t * 16 + cn;
        float bb = bias[col];
#pragma unroll
        for (int i = 0; i < 4; i++) {
            int row = m_base + quad * 4 + i;
            long o  = (long)row * 512 + col;
            float v = x1[o] + acc[t][i] + bb;
            if (f) ((float*)out)[o] = v;
            else   ((bf16_t*)out)[o] = (bf16_t)v;
        }
    }
}

// ---------------- Kernel 3: windowed attention ----------------
__global__ __launch_bounds__(256) void k_attn(const bf16_t* __restrict__ qkv,
                                              const float* __restrict__ rpb,
                                              bf16_t* __restrict__ O) {
    __shared__ float q[16][68], k[16][68], v[16][68];
    __shared__ float S[16][17];

    int blk = blockIdx.x;
    int h   = blk & 7;
    int w   = blk >> 3;
    int tid = threadIdx.x;

    int n0 = tid >> 4;
    int d0 = (tid & 15) * 4;
    const bf16_t* base = qkv + (long)(w * 16 + n0) * 1536 + h * 64 + d0;
#pragma unroll
    for (int j = 0; j < 4; j++) {
        q[n0][d0 + j] = (float)base[j] * 0.125f;
        k[n0][d0 + j] = (float)base[512 + j];
        v[n0][d0 + j] = (float)base[1024 + j];
    }
    __syncthreads();

    int i = tid >> 4, j = tid & 15;
    float s = 0.f;
#pragma unroll
    for (int d = 0; d < 64; d++) s += q[i][d] * k[j][d];

    int iy = i >> 2, ix = i & 3, jy = j >> 2, jx = j & 3;
    s += rpb[((iy - jy + 3) * 7 + (ix - jx + 3)) * 8 + h];

    int wl = w & 511;
    int wy = wl >> 5, wx = wl & 31;
    int yi = wy * 4 + iy, xi = wx * 4 + ix;
    int yj = wy * 4 + jy, xj = wx * 4 + jx;
    int ri = (yi < 60 ? 0 : (yi < 62 ? 1 : 2)) * 3 + (xi < 124 ? 0 : (xi < 126 ? 1 : 2));
    int rj = (yj < 60 ? 0 : (yj < 62 ? 1 : 2)) * 3 + (xj < 124 ? 0 : (xj < 126 ? 1 : 2));
    if (ri != rj) s -= 100.f;
    S[i][j] = s;
    __syncthreads();

    if (tid < 16) {
        float mx = -1e30f;
#pragma unroll
        for (int c = 0; c < 16; c++) mx = fmaxf(mx, S[tid][c]);
        float sum = 0.f;
#pragma unroll
        for (int c = 0; c < 16; c++) { float e = expf(S[tid][c] - mx); S[tid][c] = e; sum += e; }
        float invs = 1.f / sum;
#pragma unroll
        for (int c = 0; c < 16; c++) S[tid][c] *= invs;
    }
    __syncthreads();

#pragma unroll
    for (int t = 0; t < 4; t++) {
        int e  = tid + t * 256;
        int oi = e >> 6, od = e & 63;
        float acc = 0.f;
#pragma unroll
        for (int c = 0; c < 16; c++) acc += S[oi][c] * v[c][od];
        O[(long)(w * 16 + oi) * 512 + h * 64 + od] = (bf16_t)acc;
    }
}

// ---------------------------------------------------------------------------
extern "C" void kernel_launch(void* const* d_in, const int* in_sizes, int n_in,
                              void* d_out, int out_size, void* d_ws, size_t ws_size,
                              hipStream_t stream) {
    char* ws = (char*)d_ws;
    float*  xf   = (float*)(ws + XF_OFF);     // xf -> x1 in place
    bf16_t* xw   = (bf16_t*)(ws + XW_OFF);    // xw -> O -> h2
    bf16_t* qkv  = (bf16_t*)(ws + QKV_OFF);   // qkv -> gelu-out a
    bf16_t* wq_b = (bf16_t*)(ws + WQ_OFF);
    bf16_t* wp_b = (bf16_t*)(ws + WP_OFF);
    bf16_t* w1_b = (bf16_t*)(ws + W1_OFF);
    bf16_t* w2_b = (bf16_t*)(ws + W2_OFF);
    float*  sv   = (float*)(ws + SV_OFF);
    int*    flag = (int*)(ws + FLAG_OFF);

    // dtype probe + input normalization
    k_probe<<<1, 256, 0, stream>>>((const unsigned short*)d_in[0], 4096, flag);
    k_cvt_f32 <<<65536, 256, 0, stream>>>(d_in[0], xf, 16777216, flag);
    k_cvt_bf16<<<3072,  256, 0, stream>>>(d_in[3], wq_b, 786432, flag);
    k_cvt_bf16<<<1024,  256, 0, stream>>>(d_in[6], wp_b, 262144, flag);
    k_cvt_bf16<<<2048,  256, 0, stream>>>(d_in[10], w1_b, 524288, flag);
    k_cvt_bf16<<<2048,  256, 0, stream>>>(d_in[12], w2_b, 524288, flag);
    k_cvt_small<<<24,   256, 0, stream>>>(d_in[1], d_in[2], d_in[4], d_in[7],
                                          d_in[8], d_in[9], d_in[11], d_in[13],
                                          d_in[5], sv, flag);

    // main pipeline
    k_ln1     <<<dim3(8192),    dim3(256), 0, stream>>>(xf, sv, sv + 512, xw);
    k_gemm_qkv<<<dim3(24, 512), dim3(256), 0, stream>>>(xw, wq_b, sv + 1024, qkv, 1536, 512);
    k_attn    <<<dim3(16384),   dim3(256), 0, stream>>>(qkv, sv + 5632, xw /*O*/);
    k_gemm_proj<<<dim3(8, 512), dim3(256), 0, stream>>>(xw, wp_b, sv + 2560, xf /*x1*/, 512, 512);
    k_ln2     <<<dim3(8192),    dim3(256), 0, stream>>>(xf, sv + 3072, sv + 3584, xw /*h2*/);
    k_gemm_fc1<<<dim3(16, 512), dim3(256), 0, stream>>>(xw, w1_b, sv + 4096, qkv /*a*/, 1024, 512);
    k_gemm_fc2<<<dim3(8, 512),  dim3(256), 0, stream>>>(qkv, w2_b, sv + 5120, xf, d_out, flag, 512, 1024);
}

// Round 3
// 578.752 us; speedup vs baseline: 2.4583x; 2.4583x over previous
//
#include <hip/hip_runtime.h>
#include <hip/hip_bf16.h>
#include <math.h>

typedef __bf16 bf16_t;
typedef __bf16 bf16x8 __attribute__((ext_vector_type(8)));
typedef float f32x4 __attribute__((ext_vector_type(4)));

// ---------------------------------------------------------------------------
// Problem constants: B=4, H=64, W=128, C=512, F=1024, WS=4, SS=2, NH=8, hd=64.
// M = 32768 token rows. 2048 windows total.
// ---------------------------------------------------------------------------

// Workspace layout (bytes):
#define X1_OFF   0u            // x1 fp32 residual [32768,512] = 64 MB
#define XW_OFF   67108864u     // xw -> O -> h2 (bf16, 32 MB)
#define QKV_OFF  100663296u    // qkv -> gelu-out a (bf16, 96 MB)
#define WQ_OFF   201326592u
#define WP_OFF   202899456u
#define W1_OFF   203423744u
#define W2_OFF   204472320u
#define SV_OFF   205520896u
#define FLAG_OFF 205545472u
// SV float offsets: g1=0 be1=512 bq=1024 bp=2560 g2=3072 be2=3584 b1=4096
//                   b2=5120 rpb=5632 (end 6024)

// Gather permutation: xw row r <-> original token row perm(r).
__device__ __forceinline__ int perm_row(int r) {
    int b   = r >> 13;
    int rem = r & 8191;
    int w   = rem >> 4;
    int n   = rem & 15;
    int wy  = w >> 5, wx = w & 31;
    int y   = wy * 4 + (n >> 2);
    int x   = wx * 4 + (n & 3);
    int ys  = (y + 2) & 63;
    int xs  = (x + 2) & 127;
    return (b << 13) + (ys << 7) + xs;
}

// global->LDS direct load, 16 B per lane. LDS dest = wave-uniform base + lane*16.
// CK idiom: generic->as(1)/as(3) via uintptr round-trip (LDS aperture low bits = 0).
__device__ __forceinline__ void gld16(const void* g, void* l) {
    __builtin_amdgcn_global_load_lds(
        (const __attribute__((address_space(1))) unsigned int*)(unsigned long long)(uintptr_t)g,
        (__attribute__((address_space(3))) unsigned int*)(unsigned int)(uintptr_t)l,
        16, 0, 0);
}

// ---------------- dtype probe: 1 = fp32 source, 0 = bf16 source ----------------
__global__ __launch_bounds__(256) void k_probe(const unsigned short* __restrict__ x,
                                               int n, int* __restrict__ flag) {
    __shared__ int cnt;
    if (threadIdx.x == 0) cnt = 0;
    __syncthreads();
    int c = 0;
    for (int i = threadIdx.x; i < n; i += 256) {
        int e = (x[i] >> 7) & 0xFF;
        if (e >= 0xC0) c++;
    }
    atomicAdd(&cnt, c);
    __syncthreads();
    if (threadIdx.x == 0) *flag = (cnt > 8) ? 1 : 0;
}

// ---------------- weight / small-vector normalization ----------------
__global__ __launch_bounds__(256) void k_cvt_bf16(const void* __restrict__ src,
                                                  bf16_t* __restrict__ dst, int n,
                                                  const int* __restrict__ flag) {
    int i = blockIdx.x * 256 + threadIdx.x;
    if (i >= n) return;
    dst[i] = (*flag) ? (bf16_t)((const float*)src)[i] : ((const bf16_t*)src)[i];
}

__global__ __launch_bounds__(256) void k_cvt_small(
        const void* g1, const void* be1, const void* bq, const void* bp,
        const void* g2, const void* be2, const void* b1, const void* b2,
        const void* rpb, float* __restrict__ dst, const int* __restrict__ flag) {
    int i = blockIdx.x * 256 + threadIdx.x;
    const void* src; int off;
    if      (i < 512)  { src = g1;  off = i; }
    else if (i < 1024) { src = be1; off = i - 512; }
    else if (i < 2560) { src = bq;  off = i - 1024; }
    else if (i < 3072) { src = bp;  off = i - 2560; }
    else if (i < 3584) { src = g2;  off = i - 3072; }
    else if (i < 4096) { src = be2; off = i - 3584; }
    else if (i < 5120) { src = b1;  off = i - 4096; }
    else if (i < 5632) { src = b2;  off = i - 5120; }
    else if (i < 6024) { src = rpb; off = i - 5632; }
    else return;
    dst[i] = (*flag) ? ((const float*)src)[off] : (float)((const bf16_t*)src)[off];
}

// ---------------- Kernel 1: LN1 + shift + window partition (raw x in) ------
__global__ __launch_bounds__(256) void k_ln1(const void* __restrict__ x,
                                             const float* __restrict__ g,
                                             const float* __restrict__ be,
                                             bf16_t* __restrict__ xw,
                                             const int* __restrict__ flag) {
    int r    = blockIdx.x * 4 + (threadIdx.x >> 6);
    int lane = threadIdx.x & 63;
    int f    = *flag;
    long ro  = (long)perm_row(r) * 512;
    const float*  x32 = (const float*)x + ro;
    const bf16_t* x16 = (const bf16_t*)x + ro;
    int base = lane * 8;
    float v[8];
    float s = 0.f, ss = 0.f;
#pragma unroll
    for (int j = 0; j < 8; j++) {
        float t = f ? x32[base + j] : (float)x16[base + j];
        v[j] = t; s += t; ss += t * t;
    }
#pragma unroll
    for (int off = 32; off; off >>= 1) {
        s  += __shfl_down(s,  off, 64);
        ss += __shfl_down(ss, off, 64);
    }
    s  = __shfl(s, 0, 64);
    ss = __shfl(ss, 0, 64);
    float m   = s * (1.f / 512.f);
    float var = ss * (1.f / 512.f) - m * m;
    float inv = rsqrtf(var + 1e-5f);
    bf16_t* orow = xw + (long)r * 512;
#pragma unroll
    for (int j = 0; j < 8; j++)
        orow[base + j] = (bf16_t)((v[j] - m) * inv * g[base + j] + be[base + j]);
}

// ---------------- Kernel 5: LN2 (fp32 x1 in) ----------------
__global__ __launch_bounds__(256) void k_ln2(const float* __restrict__ x1,
                                             const float* __restrict__ g,
                                             const float* __restrict__ be,
                                             bf16_t* __restrict__ h2) {
    int r    = blockIdx.x * 4 + (threadIdx.x >> 6);
    int lane = threadIdx.x & 63;
    const float* xr = x1 + (long)r * 512;
    int base = lane * 8;
    float v[8];
    float s = 0.f, ss = 0.f;
#pragma unroll
    for (int j = 0; j < 8; j++) {
        float t = xr[base + j];
        v[j] = t; s += t; ss += t * t;
    }
#pragma unroll
    for (int off = 32; off; off >>= 1) {
        s  += __shfl_down(s,  off, 64);
        ss += __shfl_down(ss, off, 64);
    }
    s  = __shfl(s, 0, 64);
    ss = __shfl(ss, 0, 64);
    float m   = s * (1.f / 512.f);
    float var = ss * (1.f / 512.f) - m * m;
    float inv = rsqrtf(var + 1e-5f);
    bf16_t* orow = h2 + (long)r * 512;
#pragma unroll
    for (int j = 0; j < 8; j++)
        orow[base + j] = (bf16_t)((v[j] - m) * inv * g[base + j] + be[base + j]);
}

// ---------------- 128x128-tile LDS-staged MFMA GEMM (m97 structure) --------
// C = A @ W^T.  A:[M,K] bf16 row-major, W:[N,K] bf16 row-major.
// Block = 256 threads = 4 waves in 2x2; each wave owns a 64x64 quadrant
// (4x4 tiles of 16x16x32 MFMA). BK=32. LDS: sA/sB 128x32 bf16 row-major.
// Staging: thread t loads 16 B; row=t>>2 (+64 in round 1), kcol=(t&3)*8;
// LDS offset = t*16 B (+4096) == wave-uniform base (wv*1024) + lane*16. 
// EPI: 0=bias->bf16 (qkv)  1=proj: x1[perm] = raw_x + acc + bias (fp32 out)
//      2=bias+exact GELU->bf16 (fc1)  3=fc2: out = x1 + acc + bias (flag dtype)
template<int EPI>
__global__ __launch_bounds__(256) void k_gemm128(const bf16_t* __restrict__ A,
                                                 const bf16_t* __restrict__ Wt,
                                                 const float* __restrict__ bias,
                                                 void* __restrict__ out,
                                                 const void* __restrict__ res,
                                                 const int* __restrict__ flag,
                                                 int N, int K) {
    __shared__ bf16_t sA[128 * 32];
    __shared__ bf16_t sB[128 * 32];
    int tid  = threadIdx.x;
    int lane = tid & 63, wv = tid >> 6;
    int m0 = blockIdx.y * 128, n0 = blockIdx.x * 128;

    // staging addresses
    int srow = tid >> 2;
    int scol = (tid & 3) * 8;
    const bf16_t* gA0 = A  + (long)(m0 + srow) * K + scol;
    const bf16_t* gA1 = gA0 + (long)64 * K;
    const bf16_t* gB0 = Wt + (long)(n0 + srow) * K + scol;
    const bf16_t* gB1 = gB0 + (long)64 * K;
    bf16_t* lA0 = sA + wv * 512;          // bytes wv*1024, lane scatter *16
    bf16_t* lA1 = sA + 2048 + wv * 512;   // +4096 B
    bf16_t* lB0 = sB + wv * 512;
    bf16_t* lB1 = sB + 2048 + wv * 512;

    // fragment read addresses
    int rr = lane & 15, quad = lane >> 4;
    int wm = (wv >> 1) * 64, wn = (wv & 1) * 64;
    const bf16_t* rA = sA + (wm + rr) * 32 + quad * 8;
    const bf16_t* rB = sB + (wn + rr) * 32 + quad * 8;

    f32x4 acc[4][4];
#pragma unroll
    for (int mi = 0; mi < 4; mi++)
#pragma unroll
        for (int ni = 0; ni < 4; ni++) { f32x4 z = {0.f,0.f,0.f,0.f}; acc[mi][ni] = z; }

    for (int k0 = 0; k0 < K; k0 += 32) {
        gld16(gA0, lA0); gld16(gA1, lA1);
        gld16(gB0, lB0); gld16(gB1, lB1);
        gA0 += 32; gA1 += 32; gB0 += 32; gB1 += 32;
        __syncthreads();                     // staging visible (vmcnt drained)
        bf16x8 af[4], bf[4];
#pragma unroll
        for (int i = 0; i < 4; i++) af[i] = *(const bf16x8*)(rA + i * 16 * 32);
#pragma unroll
        for (int i = 0; i < 4; i++) bf[i] = *(const bf16x8*)(rB + i * 16 * 32);
#pragma unroll
        for (int mi = 0; mi < 4; mi++)
#pragma unroll
            for (int ni = 0; ni < 4; ni++)
                acc[mi][ni] = __builtin_amdgcn_mfma_f32_16x16x32_bf16(af[mi], bf[ni], acc[mi][ni], 0, 0, 0);
        __syncthreads();                     // compute done before next overwrite
    }

    int f = (EPI == 1 || EPI == 3) ? *flag : 0;
#pragma unroll
    for (int ni = 0; ni < 4; ni++) {
        int col  = n0 + wn + ni * 16 + rr;
        float bb = bias[col];
#pragma unroll
        for (int mi = 0; mi < 4; mi++) {
#pragma unroll
            for (int i = 0; i < 4; i++) {
                int row  = m0 + wm + mi * 16 + quad * 4 + i;
                float v  = acc[mi][ni][i] + bb;
                if (EPI == 0) {
                    ((bf16_t*)out)[(long)row * N + col] = (bf16_t)v;
                } else if (EPI == 1) {
                    long o   = (long)perm_row(row) * 512 + col;
                    float xv = f ? ((const float*)res)[o] : (float)((const bf16_t*)res)[o];
                    ((float*)out)[o] = xv + v;
                } else if (EPI == 2) {
                    float ge = 0.5f * v * (1.f + erff(v * 0.70710678118654752f));
                    ((bf16_t*)out)[(long)row * N + col] = (bf16_t)ge;
                } else {
                    long o   = (long)row * 512 + col;
                    float vv = ((const float*)res)[o] + v;
                    if (f) ((float*)out)[o] = vv;
                    else   ((bf16_t*)out)[o] = (bf16_t)vv;
                }
            }
        }
    }
}

// ---------------- Kernel 3: windowed attention ----------------
__global__ __launch_bounds__(256) void k_attn(const bf16_t* __restrict__ qkv,
                                              const float* __restrict__ rpb,
                                              bf16_t* __restrict__ O) {
    __shared__ float q[16][68], k[16][68], v[16][68];
    __shared__ float S[16][17];

    int blk = blockIdx.x;
    int h   = blk & 7;
    int w   = blk >> 3;
    int tid = threadIdx.x;

    int n0 = tid >> 4;
    int d0 = (tid & 15) * 4;
    const bf16_t* base = qkv + (long)(w * 16 + n0) * 1536 + h * 64 + d0;
#pragma unroll
    for (int j = 0; j < 4; j++) {
        q[n0][d0 + j] = (float)base[j] * 0.125f;
        k[n0][d0 + j] = (float)base[512 + j];
        v[n0][d0 + j] = (float)base[1024 + j];
    }
    __syncthreads();

    int i = tid >> 4, j = tid & 15;
    float s = 0.f;
#pragma unroll
    for (int d = 0; d < 64; d++) s += q[i][d] * k[j][d];

    int iy = i >> 2, ix = i & 3, jy = j >> 2, jx = j & 3;
    s += rpb[((iy - jy + 3) * 7 + (ix - jx + 3)) * 8 + h];

    int wl = w & 511;
    int wy = wl >> 5, wx = wl & 31;
    int yi = wy * 4 + iy, xi = wx * 4 + ix;
    int yj = wy * 4 + jy, xj = wx * 4 + jx;
    int ri = (yi < 60 ? 0 : (yi < 62 ? 1 : 2)) * 3 + (xi < 124 ? 0 : (xi < 126 ? 1 : 2));
    int rj = (yj < 60 ? 0 : (yj < 62 ? 1 : 2)) * 3 + (xj < 124 ? 0 : (xj < 126 ? 1 : 2));
    if (ri != rj) s -= 100.f;
    S[i][j] = s;
    __syncthreads();

    if (tid < 16) {
        float mx = -1e30f;
#pragma unroll
        for (int c = 0; c < 16; c++) mx = fmaxf(mx, S[tid][c]);
        float sum = 0.f;
#pragma unroll
        for (int c = 0; c < 16; c++) { float e = expf(S[tid][c] - mx); S[tid][c] = e; sum += e; }
        float invs = 1.f / sum;
#pragma unroll
        for (int c = 0; c < 16; c++) S[tid][c] *= invs;
    }
    __syncthreads();

#pragma unroll
    for (int t = 0; t < 4; t++) {
        int e  = tid + t * 256;
        int oi = e >> 6, od = e & 63;
        float acc = 0.f;
#pragma unroll
        for (int c = 0; c < 16; c++) acc += S[oi][c] * v[c][od];
        O[(long)(w * 16 + oi) * 512 + h * 64 + od] = (bf16_t)acc;
    }
}

// ---------------------------------------------------------------------------
extern "C" void kernel_launch(void* const* d_in, const int* in_sizes, int n_in,
                              void* d_out, int out_size, void* d_ws, size_t ws_size,
                              hipStream_t stream) {
    char* ws = (char*)d_ws;
    float*  x1   = (float*)(ws + X1_OFF);
    bf16_t* xw   = (bf16_t*)(ws + XW_OFF);    // xw -> O -> h2
    bf16_t* qkv  = (bf16_t*)(ws + QKV_OFF);   // qkv -> gelu-out a
    bf16_t* wq_b = (bf16_t*)(ws + WQ_OFF);
    bf16_t* wp_b = (bf16_t*)(ws + WP_OFF);
    bf16_t* w1_b = (bf16_t*)(ws + W1_OFF);
    bf16_t* w2_b = (bf16_t*)(ws + W2_OFF);
    float*  sv   = (float*)(ws + SV_OFF);
    int*    flag = (int*)(ws + FLAG_OFF);

    // dtype probe + weight normalization
    k_probe<<<1, 256, 0, stream>>>((const unsigned short*)d_in[0], 4096, flag);
    k_cvt_bf16<<<3072, 256, 0, stream>>>(d_in[3],  wq_b, 786432, flag);
    k_cvt_bf16<<<1024, 256, 0, stream>>>(d_in[6],  wp_b, 262144, flag);
    k_cvt_bf16<<<2048, 256, 0, stream>>>(d_in[10], w1_b, 524288, flag);
    k_cvt_bf16<<<2048, 256, 0, stream>>>(d_in[12], w2_b, 524288, flag);
    k_cvt_small<<<24,  256, 0, stream>>>(d_in[1], d_in[2], d_in[4], d_in[7],
                                         d_in[8], d_in[9], d_in[11], d_in[13],
                                         d_in[5], sv, flag);

    // main pipeline
    k_ln1<<<dim3(8192), dim3(256), 0, stream>>>(d_in[0], sv, sv + 512, xw, flag);
    k_gemm128<0><<<dim3(12, 256), dim3(256), 0, stream>>>(xw, wq_b, sv + 1024, qkv, nullptr, flag, 1536, 512);
    k_attn<<<dim3(16384), dim3(256), 0, stream>>>(qkv, sv + 5632, xw /*O*/);
    k_gemm128<1><<<dim3(4, 256), dim3(256), 0, stream>>>(xw, wp_b, sv + 2560, x1, d_in[0], flag, 512, 512);
    k_ln2<<<dim3(8192), dim3(256), 0, stream>>>(x1, sv + 3072, sv + 3584, xw /*h2*/);
    k_gemm128<2><<<dim3(8, 256), dim3(256), 0, stream>>>(xw, w1_b, sv + 4096, qkv /*a*/, nullptr, flag, 1024, 512);
    k_gemm128<3><<<dim3(4, 256), dim3(256), 0, stream>>>(qkv, w2_b, sv + 5120, d_out, x1, flag, 512, 1024);
}

// Round 4
// 544.003 us; speedup vs baseline: 2.6153x; 1.0639x over previous
//
#include <hip/hip_runtime.h>
#include <hip/hip_bf16.h>
#include <math.h>

typedef __bf16 bf16_t;
typedef __bf16 bf16x8 __attribute__((ext_vector_type(8)));
typedef float f32x4 __attribute__((ext_vector_type(4)));

// ---------------------------------------------------------------------------
// Problem constants: B=4, H=64, W=128, C=512, F=1024, WS=4, SS=2, NH=8, hd=64.
// M = 32768 token rows. 2048 windows total.
// ---------------------------------------------------------------------------

#define X1_OFF   0u            // x1 fp32 residual [32768,512] = 64 MB
#define XW_OFF   67108864u     // xw -> O -> h2 (bf16, 32 MB)
#define QKV_OFF  100663296u    // qkv -> gelu-out a (bf16, 96 MB)
#define WQ_OFF   201326592u
#define WP_OFF   202899456u
#define W1_OFF   203423744u
#define W2_OFF   204472320u
#define SV_OFF   205520896u
#define FLAG_OFF 205545472u
// SV float offsets: g1=0 be1=512 bq=1024 bp=2560 g2=3072 be2=3584 b1=4096
//                   b2=5120 rpb=5632 (end 6024)

__device__ __forceinline__ int perm_row(int r) {
    int b   = r >> 13;
    int rem = r & 8191;
    int w   = rem >> 4;
    int n   = rem & 15;
    int wy  = w >> 5, wx = w & 31;
    int y   = wy * 4 + (n >> 2);
    int x   = wx * 4 + (n & 3);
    int ys  = (y + 2) & 63;
    int xs  = (x + 2) & 127;
    return (b << 13) + (ys << 7) + xs;
}

// global->LDS direct load, 16 B per lane: pass per-lane global addr + wave-uniform
// LDS base; HW scatters lane i -> base + i*16.
__device__ __forceinline__ void gld16(const void* g, void* l) {
    __builtin_amdgcn_global_load_lds(
        (const __attribute__((address_space(1))) unsigned int*)(unsigned long long)(uintptr_t)g,
        (__attribute__((address_space(3))) unsigned int*)(unsigned int)(uintptr_t)l,
        16, 0, 0);
}

// ---------------- dtype probe: 1 = fp32 source, 0 = bf16 source ----------------
__global__ __launch_bounds__(256) void k_probe(const unsigned short* __restrict__ x,
                                               int n, int* __restrict__ flag) {
    __shared__ int cnt;
    if (threadIdx.x == 0) cnt = 0;
    __syncthreads();
    int c = 0;
    for (int i = threadIdx.x; i < n; i += 256) {
        int e = (x[i] >> 7) & 0xFF;
        if (e >= 0xC0) c++;
    }
    atomicAdd(&cnt, c);
    __syncthreads();
    if (threadIdx.x == 0) *flag = (cnt > 8) ? 1 : 0;
}

// ---------------- weight / small-vector normalization ----------------
__global__ __launch_bounds__(256) void k_cvt_bf16(const void* __restrict__ src,
                                                  bf16_t* __restrict__ dst, int n,
                                                  const int* __restrict__ flag) {
    int i = blockIdx.x * 256 + threadIdx.x;
    if (i >= n) return;
    dst[i] = (*flag) ? (bf16_t)((const float*)src)[i] : ((const bf16_t*)src)[i];
}

__global__ __launch_bounds__(256) void k_cvt_small(
        const void* g1, const void* be1, const void* bq, const void* bp,
        const void* g2, const void* be2, const void* b1, const void* b2,
        const void* rpb, float* __restrict__ dst, const int* __restrict__ flag) {
    int i = blockIdx.x * 256 + threadIdx.x;
    const void* src; int off;
    if      (i < 512)  { src = g1;  off = i; }
    else if (i < 1024) { src = be1; off = i - 512; }
    else if (i < 2560) { src = bq;  off = i - 1024; }
    else if (i < 3072) { src = bp;  off = i - 2560; }
    else if (i < 3584) { src = g2;  off = i - 3072; }
    else if (i < 4096) { src = be2; off = i - 3584; }
    else if (i < 5120) { src = b1;  off = i - 4096; }
    else if (i < 5632) { src = b2;  off = i - 5120; }
    else if (i < 6024) { src = rpb; off = i - 5632; }
    else return;
    dst[i] = (*flag) ? ((const float*)src)[off] : (float)((const bf16_t*)src)[off];
}

// ---------------- Kernel 1: LN1 + shift + window partition ----------------
__global__ __launch_bounds__(256) void k_ln1(const void* __restrict__ x,
                                             const float* __restrict__ g,
                                             const float* __restrict__ be,
                                             bf16_t* __restrict__ xw,
                                             const int* __restrict__ flag) {
    int r    = blockIdx.x * 4 + (threadIdx.x >> 6);
    int lane = threadIdx.x & 63;
    int f    = *flag;
    long ro  = (long)perm_row(r) * 512;
    const float*  x32 = (const float*)x + ro;
    const bf16_t* x16 = (const bf16_t*)x + ro;
    int base = lane * 8;
    float v[8];
    float s = 0.f, ss = 0.f;
#pragma unroll
    for (int j = 0; j < 8; j++) {
        float t = f ? x32[base + j] : (float)x16[base + j];
        v[j] = t; s += t; ss += t * t;
    }
#pragma unroll
    for (int off = 32; off; off >>= 1) {
        s  += __shfl_down(s,  off, 64);
        ss += __shfl_down(ss, off, 64);
    }
    s  = __shfl(s, 0, 64);
    ss = __shfl(ss, 0, 64);
    float m   = s * (1.f / 512.f);
    float var = ss * (1.f / 512.f) - m * m;
    float inv = rsqrtf(var + 1e-5f);
    bf16_t* orow = xw + (long)r * 512;
#pragma unroll
    for (int j = 0; j < 8; j++)
        orow[base + j] = (bf16_t)((v[j] - m) * inv * g[base + j] + be[base + j]);
}

// ---------------- Kernel 5: LN2 ----------------
__global__ __launch_bounds__(256) void k_ln2(const float* __restrict__ x1,
                                             const float* __restrict__ g,
                                             const float* __restrict__ be,
                                             bf16_t* __restrict__ h2) {
    int r    = blockIdx.x * 4 + (threadIdx.x >> 6);
    int lane = threadIdx.x & 63;
    const float* xr = x1 + (long)r * 512;
    int base = lane * 8;
    float v[8];
    float s = 0.f, ss = 0.f;
#pragma unroll
    for (int j = 0; j < 8; j++) {
        float t = xr[base + j];
        v[j] = t; s += t; ss += t * t;
    }
#pragma unroll
    for (int off = 32; off; off >>= 1) {
        s  += __shfl_down(s,  off, 64);
        ss += __shfl_down(ss, off, 64);
    }
    s  = __shfl(s, 0, 64);
    ss = __shfl(ss, 0, 64);
    float m   = s * (1.f / 512.f);
    float var = ss * (1.f / 512.f) - m * m;
    float inv = rsqrtf(var + 1e-5f);
    bf16_t* orow = h2 + (long)r * 512;
#pragma unroll
    for (int j = 0; j < 8; j++)
        orow[base + j] = (bf16_t)((v[j] - m) * inv * g[base + j] + be[base + j]);
}

// ---------------- 128x128-tile GEMM, BK=64, XOR-swizzled LDS, XCD swizzle --
// C = A @ W^T.  A:[M,K] bf16 rm, W:[N,K] bf16 rm. 4 waves in 2x2, each a
// 64x64 quadrant of 16x16x32 MFMAs. Grid is 1D = (N/128)*(M/128); block id
// is swizzled so all column-blocks of one row-stripe land on one XCD
// (id%8 == y%8) -> A-tile re-reads hit that XCD's L2.
// LDS row r holds k-chunks in XOR order: pos p stores global chunk p^(r&7);
// staging thread t (call j): row=j*32+(t>>3), chunk=(t&7)^((t>>3)&7) -> each
// 8-thread group reads one contiguous 128B row segment (coalesced), and
// fragment ds_read_b128s spread evenly over all 32 banks (2-way only).
// EPI: 0=bias->bf16  1=proj: x1[perm]=x+acc+bias (fp32)  2=bias+GELU->bf16
//      3=fc2: out=x1+acc+bias (flag dtype)
template<int EPI>
__global__ __launch_bounds__(256) void k_gemm128(const bf16_t* __restrict__ A,
                                                 const bf16_t* __restrict__ Wt,
                                                 const float* __restrict__ bias,
                                                 void* __restrict__ out,
                                                 const void* __restrict__ res,
                                                 const int* __restrict__ flag,
                                                 int N, int K) {
    __shared__ bf16_t sA[128 * 64];
    __shared__ bf16_t sB[128 * 64];
    int tid  = threadIdx.x;
    int lane = tid & 63, wv = tid >> 6;

    int nbx = N >> 7;
    int id  = blockIdx.x;
    int xb  = (id >> 3) % nbx;
    int yb  = ((id >> 3) / nbx) * 8 + (id & 7);
    int m0  = yb << 7, n0 = xb << 7;

    // staging
    int srow = tid >> 3;                 // 0..31
    int kc   = (tid & 7) ^ (srow & 7);   // XOR-swizzled chunk
    const bf16_t* gA = A  + (long)(m0 + srow) * K + kc * 8;
    const bf16_t* gB = Wt + (long)(n0 + srow) * K + kc * 8;

    // fragment reads
    int rr = lane & 15, quad = lane >> 4;
    int wm = (wv >> 1) * 64, wn = (wv & 1) * 64;
    int p0 = ((quad ^ (rr & 7)) * 8);    // element offset of k-chunk, ks=0
    const bf16_t* rA = sA + (wm + rr) * 64;
    const bf16_t* rB = sB + (wn + rr) * 64;

    f32x4 acc[4][4];
#pragma unroll
    for (int mi = 0; mi < 4; mi++)
#pragma unroll
        for (int ni = 0; ni < 4; ni++) { f32x4 z = {0.f,0.f,0.f,0.f}; acc[mi][ni] = z; }

    for (int k0 = 0; k0 < K; k0 += 64) {
#pragma unroll
        for (int j = 0; j < 4; j++) {
            gld16(gA + (long)j * 32 * K, sA + j * 2048 + wv * 512);
            gld16(gB + (long)j * 32 * K, sB + j * 2048 + wv * 512);
        }
        gA += 64; gB += 64;
        __syncthreads();
#pragma unroll
        for (int ks = 0; ks < 2; ks++) {
            int pp = ks ? (p0 ^ 32) : p0;   // chunk XOR 4 == element offset XOR 32
            bf16x8 af[4], bg[4];
#pragma unroll
            for (int i = 0; i < 4; i++) af[i] = *(const bf16x8*)(rA + i * 1024 + pp);
#pragma unroll
            for (int i = 0; i < 4; i++) bg[i] = *(const bf16x8*)(rB + i * 1024 + pp);
#pragma unroll
            for (int mi = 0; mi < 4; mi++)
#pragma unroll
                for (int ni = 0; ni < 4; ni++)
                    acc[mi][ni] = __builtin_amdgcn_mfma_f32_16x16x32_bf16(af[mi], bg[ni], acc[mi][ni], 0, 0, 0);
        }
        __syncthreads();
    }

    int f = (EPI == 1 || EPI == 3) ? *flag : 0;
#pragma unroll
    for (int ni = 0; ni < 4; ni++) {
        int col  = n0 + wn + ni * 16 + rr;
        float bb = bias[col];
#pragma unroll
        for (int mi = 0; mi < 4; mi++) {
#pragma unroll
            for (int i = 0; i < 4; i++) {
                int row  = m0 + wm + mi * 16 + quad * 4 + i;
                float v  = acc[mi][ni][i] + bb;
                if (EPI == 0) {
                    ((bf16_t*)out)[(long)row * N + col] = (bf16_t)v;
                } else if (EPI == 1) {
                    long o   = (long)perm_row(row) * 512 + col;
                    float xv = f ? ((const float*)res)[o] : (float)((const bf16_t*)res)[o];
                    ((float*)out)[o] = xv + v;
                } else if (EPI == 2) {
                    float ge = 0.5f * v * (1.f + erff(v * 0.70710678118654752f));
                    ((bf16_t*)out)[(long)row * N + col] = (bf16_t)ge;
                } else {
                    long o   = (long)row * 512 + col;
                    float vv = ((const float*)res)[o] + v;
                    if (f) ((float*)out)[o] = vv;
                    else   ((bf16_t*)out)[o] = (bf16_t)vv;
                }
            }
        }
    }
}

// ---------------- Kernel 3: windowed attention ----------------
__global__ __launch_bounds__(256) void k_attn(const bf16_t* __restrict__ qkv,
                                              const float* __restrict__ rpb,
                                              bf16_t* __restrict__ O) {
    __shared__ float q[16][68], k[16][68], v[16][68];
    __shared__ float S[16][17];

    int blk = blockIdx.x;
    int h   = blk & 7;
    int w   = blk >> 3;
    int tid = threadIdx.x;

    int n0 = tid >> 4;
    int d0 = (tid & 15) * 4;
    const bf16_t* base = qkv + (long)(w * 16 + n0) * 1536 + h * 64 + d0;
#pragma unroll
    for (int j = 0; j < 4; j++) {
        q[n0][d0 + j] = (float)base[j] * 0.125f;
        k[n0][d0 + j] = (float)base[512 + j];
        v[n0][d0 + j] = (float)base[1024 + j];
    }
    __syncthreads();

    int i = tid >> 4, j = tid & 15;
    float s = 0.f;
#pragma unroll
    for (int d = 0; d < 64; d++) s += q[i][d] * k[j][d];

    int iy = i >> 2, ix = i & 3, jy = j >> 2, jx = j & 3;
    s += rpb[((iy - jy + 3) * 7 + (ix - jx + 3)) * 8 + h];

    int wl = w & 511;
    int wy = wl >> 5, wx = wl & 31;
    int yi = wy * 4 + iy, xi = wx * 4 + ix;
    int yj = wy * 4 + jy, xj = wx * 4 + jx;
    int ri = (yi < 60 ? 0 : (yi < 62 ? 1 : 2)) * 3 + (xi < 124 ? 0 : (xi < 126 ? 1 : 2));
    int rj = (yj < 60 ? 0 : (yj < 62 ? 1 : 2)) * 3 + (xj < 124 ? 0 : (xj < 126 ? 1 : 2));
    if (ri != rj) s -= 100.f;
    S[i][j] = s;
    __syncthreads();

    if (tid < 16) {
        float mx = -1e30f;
#pragma unroll
        for (int c = 0; c < 16; c++) mx = fmaxf(mx, S[tid][c]);
        float sum = 0.f;
#pragma unroll
        for (int c = 0; c < 16; c++) { float e = expf(S[tid][c] - mx); S[tid][c] = e; sum += e; }
        float invs = 1.f / sum;
#pragma unroll
        for (int c = 0; c < 16; c++) S[tid][c] *= invs;
    }
    __syncthreads();

#pragma unroll
    for (int t = 0; t < 4; t++) {
        int e  = tid + t * 256;
        int oi = e >> 6, od = e & 63;
        float acc = 0.f;
#pragma unroll
        for (int c = 0; c < 16; c++) acc += S[oi][c] * v[c][od];
        O[(long)(w * 16 + oi) * 512 + h * 64 + od] = (bf16_t)acc;
    }
}

// ---------------------------------------------------------------------------
extern "C" void kernel_launch(void* const* d_in, const int* in_sizes, int n_in,
                              void* d_out, int out_size, void* d_ws, size_t ws_size,
                              hipStream_t stream) {
    char* ws = (char*)d_ws;
    float*  x1   = (float*)(ws + X1_OFF);
    bf16_t* xw   = (bf16_t*)(ws + XW_OFF);    // xw -> O -> h2
    bf16_t* qkv  = (bf16_t*)(ws + QKV_OFF);   // qkv -> gelu-out a
    bf16_t* wq_b = (bf16_t*)(ws + WQ_OFF);
    bf16_t* wp_b = (bf16_t*)(ws + WP_OFF);
    bf16_t* w1_b = (bf16_t*)(ws + W1_OFF);
    bf16_t* w2_b = (bf16_t*)(ws + W2_OFF);
    float*  sv   = (float*)(ws + SV_OFF);
    int*    flag = (int*)(ws + FLAG_OFF);

    k_probe<<<1, 256, 0, stream>>>((const unsigned short*)d_in[0], 4096, flag);
    k_cvt_bf16<<<3072, 256, 0, stream>>>(d_in[3],  wq_b, 786432, flag);
    k_cvt_bf16<<<1024, 256, 0, stream>>>(d_in[6],  wp_b, 262144, flag);
    k_cvt_bf16<<<2048, 256, 0, stream>>>(d_in[10], w1_b, 524288, flag);
    k_cvt_bf16<<<2048, 256, 0, stream>>>(d_in[12], w2_b, 524288, flag);
    k_cvt_small<<<24,  256, 0, stream>>>(d_in[1], d_in[2], d_in[4], d_in[7],
                                         d_in[8], d_in[9], d_in[11], d_in[13],
                                         d_in[5], sv, flag);

    k_ln1<<<dim3(8192), dim3(256), 0, stream>>>(d_in[0], sv, sv + 512, xw, flag);
    k_gemm128<0><<<dim3(3072), dim3(256), 0, stream>>>(xw, wq_b, sv + 1024, qkv, nullptr, flag, 1536, 512);
    k_attn<<<dim3(16384), dim3(256), 0, stream>>>(qkv, sv + 5632, xw /*O*/);
    k_gemm128<1><<<dim3(1024), dim3(256), 0, stream>>>(xw, wp_b, sv + 2560, x1, d_in[0], flag, 512, 512);
    k_ln2<<<dim3(8192), dim3(256), 0, stream>>>(x1, sv + 3072, sv + 3584, xw /*h2*/);
    k_gemm128<2><<<dim3(2048), dim3(256), 0, stream>>>(xw, w1_b, sv + 4096, qkv /*a*/, nullptr, flag, 1024, 512);
    k_gemm128<3><<<dim3(1024), dim3(256), 0, stream>>>(qkv, w2_b, sv + 5120, d_out, x1, flag, 512, 1024);
}